// Round 2
// baseline (283.805 us; speedup 1.0000x reference)
//
#include <hip/hip_runtime.h>
#include <hip/hip_bf16.h>

#define DIN    4096
#define DOUT   11008
#define TM     64
#define KSPLIT 8
#define KCHUNK (DIN / KSPLIT)     // 512
#define NCHUNKS (DOUT / 16)       // 688

typedef __attribute__((ext_vector_type(8))) short  bf16x8;
typedef __attribute__((ext_vector_type(4))) float  f32x4;

// floor(log2(safe_amax)) - 2, clipped; scale and 1/scale are powers of 2 (exact)
__device__ inline void mx_block_scale(float amax, float& scale, float& inv_scale) {
    float safe = amax > 0.0f ? amax : 1.0f;
    int e  = (int)((__float_as_uint(safe) >> 23) & 255) - 127; // floor(log2), normals
    int se = e - 2;
    if (se < -127) se = -127;       // E8M0_MIN clip (upper clip unreachable)
    scale     = ldexpf(1.0f, se);
    inv_scale = ldexpf(1.0f, -se);
}

// E2M1 quant-dequant of one element given the block scale (exact vs jnp ref).
// step = 2^(clamp(floor(log2 a),0,2)-1) via exponent-field clamp.
__device__ inline float mx_qd(float v, float scale, float inv_scale) {
    float a = fabsf(v) * inv_scale;  // exact pow2 mult
    a = fminf(a, 6.0f);              // FP4_MAX saturate
    unsigned ebc = __float_as_uint(a) & 0x7f800000u;
    ebc = ebc < 0x3f800000u ? 0x3f800000u : ebc;       // e in {0,1,2}
    float step  = __uint_as_float(ebc - 0x00800000u);  // 2^(e-1): 0.5/1/2
    float rstep = __uint_as_float(0x7f800000u - ebc);  // 2^(1-e): 2/1/0.5
    float q = rintf(a * rstep) * step;   // round-half-even = jnp.round
    return copysignf(q * scale, v);
}

__device__ inline short bf16_trunc(float f) {
    // dequantized values have <=2 mantissa bits -> truncation exact
    return (short)(__float_as_uint(f) >> 16);
}

__device__ inline float blk_absmax8(const float4& a, const float4& b) {
    return fmaxf(fmaxf(fmaxf(fabsf(a.x), fabsf(a.y)), fmaxf(fabsf(a.z), fabsf(a.w))),
                 fmaxf(fmaxf(fabsf(b.x), fabsf(b.y)), fmaxf(fabsf(b.z), fabsf(b.w))));
}

// ---------------- kernel 1: quantize x -> bf16 in ws (exact) ----------------
__global__ __launch_bounds__(256) void quant_x_kernel(const float* __restrict__ x,
                                                      unsigned short* __restrict__ x_dq) {
    int gid = blockIdx.x * 256 + threadIdx.x;       // 65536 threads x 4 elems
    const float4 v = *(const float4*)(x + (size_t)gid * 4);
    float am = fmaxf(fmaxf(fabsf(v.x), fabsf(v.y)), fmaxf(fabsf(v.z), fabsf(v.w)));
    am = fmaxf(am, __shfl_xor(am, 1));
    am = fmaxf(am, __shfl_xor(am, 2));
    am = fmaxf(am, __shfl_xor(am, 4));              // 8-lane group = one 32-block
    float scale, inv;
    mx_block_scale(am, scale, inv);
    ushort4 q;
    q.x = (unsigned short)bf16_trunc(mx_qd(v.x, scale, inv));
    q.y = (unsigned short)bf16_trunc(mx_qd(v.y, scale, inv));
    q.z = (unsigned short)bf16_trunc(mx_qd(v.z, scale, inv));
    q.w = (unsigned short)bf16_trunc(mx_qd(v.w, scale, inv));
    *(ushort4*)(x_dq + (size_t)gid * 4) = q;
}

// ---------- kernel 2: fused W-quant GEMM + K-split reduce + bias ----------
// Block = 16 output cols (nch = blockIdx.x); wave w = K-split w (512 elems).
// KSPLIT=8 (vs 4): doubles resident waves (2.7 -> 5.4 per SIMD) to hide the
// W-prefetch HBM latency and x_dq L2-hit latency that a 2.7-wave/SIMD grid
// exposed. Total W traffic and quant VALU work unchanged.
// Epilogue: 8 waves drop 64x16 partials into LDS; one barrier; strict
// left-to-right split sum (exact f32 arithmetic - dequant values have <=4
// significant product bits) + quantized bias.
__global__ __launch_bounds__(512) void gemm_fused_kernel(const unsigned short* __restrict__ x_dq,
                                                         const float* __restrict__ wgt,
                                                         const float* __restrict__ bias,
                                                         float* __restrict__ out) {
    const int lane  = threadIdx.x & 63;
    const int wid   = threadIdx.x >> 6;             // K-split 0..7
    const int nch   = blockIdx.x;                   // 0..687
    const int nlo   = lane & 15;
    const int kq    = lane >> 4;                    // quad 0..3
    const int kbase = wid * KCHUNK + kq * 8;

    __shared__ float red[KSPLIT][TM][20];           // pad 20: 2-way max (free)
    __shared__ float bq[32];

    // quantized bias for this block's 32-wide MXFP block (cols nch*16..+15
    // are one aligned half of bias block nch>>1). Wave-0 lanes 0..31 only;
    // xor partners (1,2,4,8,16) stay inside the active half-wave.
    if (threadIdx.x < 32) {
        float v = bias[(nch >> 1) * 32 + threadIdx.x];
        float am = fabsf(v);
        am = fmaxf(am, __shfl_xor(am, 1));
        am = fmaxf(am, __shfl_xor(am, 2));
        am = fmaxf(am, __shfl_xor(am, 4));
        am = fmaxf(am, __shfl_xor(am, 8));
        am = fmaxf(am, __shfl_xor(am, 16));
        float scale, inv;
        mx_block_scale(am, scale, inv);
        bq[threadIdx.x] = mx_qd(v, scale, inv);
    }

    const float*          wp = wgt  + (size_t)(nch * 16 + nlo) * DIN + kbase;
    const unsigned short* xp = x_dq + (size_t)nlo * DIN + kbase;

    f32x4 acc0 = {0.f,0.f,0.f,0.f};
    f32x4 acc1 = {0.f,0.f,0.f,0.f};
    f32x4 acc2 = {0.f,0.f,0.f,0.f};
    f32x4 acc3 = {0.f,0.f,0.f,0.f};

    // pipeline prologue: wa = W(k), wb = W(k+32) in flight, scale for wa ready
    float4 wa0 = *(const float4*)(wp);
    float4 wa1 = *(const float4*)(wp + 4);
    float4 wb0 = *(const float4*)(wp + 32);
    float4 wb1 = *(const float4*)(wp + 36);
    float am = blk_absmax8(wa0, wa1);
    am = fmaxf(am, __shfl_xor(am, 16));
    am = fmaxf(am, __shfl_xor(am, 32));
    float scale, inv;
    mx_block_scale(am, scale, inv);

    #pragma unroll 4
    for (int kk = 0; kk < KCHUNK; kk += 32) {
        // issue W(k+64); clamp keeps the last iterations in-bounds (dup load)
        const int kpre = (kk + 64 < KCHUNK) ? kk + 64 : KCHUNK - 32;
        float4 wc0 = *(const float4*)(wp + kpre);
        float4 wc1 = *(const float4*)(wp + kpre + 4);

        // A fragments (x_dq is 512 KB, L1/L2-resident)
        bf16x8 a0 = *(const bf16x8*)(xp + kk);
        bf16x8 a1 = *(const bf16x8*)(xp + 16 * DIN + kk);
        bf16x8 a2 = *(const bf16x8*)(xp + 32 * DIN + kk);
        bf16x8 a3 = *(const bf16x8*)(xp + 48 * DIN + kk);

        // quantize current tile with the pre-computed scale
        bf16x8 bf;
        bf[0] = bf16_trunc(mx_qd(wa0.x, scale, inv));
        bf[1] = bf16_trunc(mx_qd(wa0.y, scale, inv));
        bf[2] = bf16_trunc(mx_qd(wa0.z, scale, inv));
        bf[3] = bf16_trunc(mx_qd(wa0.w, scale, inv));
        bf[4] = bf16_trunc(mx_qd(wa1.x, scale, inv));
        bf[5] = bf16_trunc(mx_qd(wa1.y, scale, inv));
        bf[6] = bf16_trunc(mx_qd(wa1.z, scale, inv));
        bf[7] = bf16_trunc(mx_qd(wa1.w, scale, inv));

        acc0 = __builtin_amdgcn_mfma_f32_16x16x32_bf16(a0, bf, acc0, 0, 0, 0);
        acc1 = __builtin_amdgcn_mfma_f32_16x16x32_bf16(a1, bf, acc1, 0, 0, 0);
        acc2 = __builtin_amdgcn_mfma_f32_16x16x32_bf16(a2, bf, acc2, 0, 0, 0);
        acc3 = __builtin_amdgcn_mfma_f32_16x16x32_bf16(a3, bf, acc3, 0, 0, 0);

        // scale for the NEXT tile (wb arrived long ago); shfl latency overlaps
        // the MFMAs just issued
        float amn = blk_absmax8(wb0, wb1);
        amn = fmaxf(amn, __shfl_xor(amn, 16));
        amn = fmaxf(amn, __shfl_xor(amn, 32));
        mx_block_scale(amn, scale, inv);

        wa0 = wb0; wa1 = wb1;
        wb0 = wc0; wb1 = wc1;
    }

    // C/D map: col(n)=lane&15, row(m)=quad*4+reg (verified: absmax 0)
    const int mrow = kq * 4;
    #pragma unroll
    for (int r = 0; r < 4; ++r) {
        red[wid][mrow + r][nlo]      = acc0[r];
        red[wid][16 + mrow + r][nlo] = acc1[r];
        red[wid][32 + mrow + r][nlo] = acc2[r];
        red[wid][48 + mrow + r][nlo] = acc3[r];
    }
    __syncthreads();

    // 2 outputs per thread; strict left-to-right split sum
    const int col  = threadIdx.x & 15;
    const int row0 = threadIdx.x >> 4;              // 0..31
    const float b  = bq[((nch & 1) << 4) + col];
    float* op = out + (size_t)nch * 16 + col;
    #pragma unroll
    for (int t = 0; t < 2; ++t) {
        const int row = row0 + 32 * t;
        float s = red[0][row][col];
        #pragma unroll
        for (int i = 1; i < KSPLIT; ++i) s += red[i][row][col];
        op[(size_t)row * DOUT] = s + b;
    }
}

extern "C" void kernel_launch(void* const* d_in, const int* in_sizes, int n_in,
                              void* d_out, int out_size, void* d_ws, size_t ws_size,
                              hipStream_t stream) {
    const float* x    = (const float*)d_in[0];   // [64, 4096]
    const float* wgt  = (const float*)d_in[1];   // [11008, 4096]
    const float* bias = (const float*)d_in[2];   // [11008]
    float* out = (float*)d_out;                  // [64, 11008]

    unsigned short* x_dq = (unsigned short*)d_ws;    // 512 KB (only ws use now)

    quant_x_kernel<<<256, 256, 0, stream>>>(x, x_dq);
    gemm_fused_kernel<<<NCHUNKS, 512, 0, stream>>>(x_dq, wgt, bias, out);
}

// Round 3
// 279.943 us; speedup vs baseline: 1.0138x; 1.0138x over previous
//
#include <hip/hip_runtime.h>
#include <hip/hip_bf16.h>

#define DIN    4096
#define DOUT   11008
#define TM     64
#define KSPLIT 4
#define KCHUNK (DIN / KSPLIT)     // 1024
#define NCHUNKS (DOUT / 16)       // 688

typedef __attribute__((ext_vector_type(8))) short  bf16x8;
typedef __attribute__((ext_vector_type(4))) float  f32x4;

// floor(log2(safe_amax)) - 2, clipped; scale and 1/scale are powers of 2 (exact)
__device__ inline void mx_block_scale(float amax, float& scale, float& inv_scale) {
    float safe = amax > 0.0f ? amax : 1.0f;
    int e  = (int)((__float_as_uint(safe) >> 23) & 255) - 127; // floor(log2), normals
    int se = e - 2;
    if (se < -127) se = -127;       // E8M0_MIN clip (upper clip unreachable)
    scale     = ldexpf(1.0f, se);
    inv_scale = ldexpf(1.0f, -se);
}

// E2M1 quant-dequant of one element given the block scale (exact vs jnp ref).
// step = 2^(clamp(floor(log2 a),0,2)-1) via exponent-field clamp.
__device__ inline float mx_qd(float v, float scale, float inv_scale) {
    float a = fabsf(v) * inv_scale;  // exact pow2 mult
    a = fminf(a, 6.0f);              // FP4_MAX saturate
    unsigned ebc = __float_as_uint(a) & 0x7f800000u;
    ebc = ebc < 0x3f800000u ? 0x3f800000u : ebc;       // e in {0,1,2}
    float step  = __uint_as_float(ebc - 0x00800000u);  // 2^(e-1): 0.5/1/2
    float rstep = __uint_as_float(0x7f800000u - ebc);  // 2^(1-e): 2/1/0.5
    float q = rintf(a * rstep) * step;   // round-half-even = jnp.round
    return copysignf(q * scale, v);
}

__device__ inline short bf16_trunc(float f) {
    // dequantized values have <=2 mantissa bits -> truncation exact
    return (short)(__float_as_uint(f) >> 16);
}

__device__ inline float blk_absmax8(const float4& a, const float4& b) {
    return fmaxf(fmaxf(fmaxf(fabsf(a.x), fabsf(a.y)), fmaxf(fabsf(a.z), fabsf(a.w))),
                 fmaxf(fmaxf(fabsf(b.x), fabsf(b.y)), fmaxf(fabsf(b.z), fabsf(b.w))));
}

__device__ inline float blk_absmax16(const float4& a, const float4& b,
                                     const float4& c, const float4& d) {
    return fmaxf(blk_absmax8(a, b), blk_absmax8(c, d));
}

// ---------------- kernel 1: quantize x -> bf16 in ws (exact) ----------------
__global__ __launch_bounds__(256) void quant_x_kernel(const float* __restrict__ x,
                                                      unsigned short* __restrict__ x_dq) {
    int gid = blockIdx.x * 256 + threadIdx.x;       // 65536 threads x 4 elems
    const float4 v = *(const float4*)(x + (size_t)gid * 4);
    float am = fmaxf(fmaxf(fabsf(v.x), fabsf(v.y)), fmaxf(fabsf(v.z), fabsf(v.w)));
    am = fmaxf(am, __shfl_xor(am, 1));
    am = fmaxf(am, __shfl_xor(am, 2));
    am = fmaxf(am, __shfl_xor(am, 4));              // 8-lane group = one 32-block
    float scale, inv;
    mx_block_scale(am, scale, inv);
    ushort4 q;
    q.x = (unsigned short)bf16_trunc(mx_qd(v.x, scale, inv));
    q.y = (unsigned short)bf16_trunc(mx_qd(v.y, scale, inv));
    q.z = (unsigned short)bf16_trunc(mx_qd(v.z, scale, inv));
    q.w = (unsigned short)bf16_trunc(mx_qd(v.w, scale, inv));
    *(ushort4*)(x_dq + (size_t)gid * 4) = q;
}

// ---------- kernel 2: fused W-quant GEMM + K-split reduce + bias ----------
// K-REMAP for coalescing: per K=64 macro-step, quad q owns the CONTIGUOUS
// physical slice k in [q*16, q*16+16). Each lane loads 64B contiguous from
// its W row (4 x float4) -> every wave load instruction covers 16 fully-used
// cachelines (vs 32 half-used before), and each row-stream advances in 256B
// contiguous chunks (DRAM page locality). MFMA pairs A(q,j) with B(q,j), so
// the contraction is correct as long as x_dq is read at the SAME offsets --
// it is (natural order, 2 contiguous bf16x8 per row-group per macro-step).
// MXFP 32-blocks stay intact: quads {0,1} = block [0,32), {2,3} = [32,64);
// scale = absmax(own 16) + one shfl_xor(16) to the partner quad.
__global__ __launch_bounds__(256) void gemm_fused_kernel(const unsigned short* __restrict__ x_dq,
                                                         const float* __restrict__ wgt,
                                                         const float* __restrict__ bias,
                                                         float* __restrict__ out) {
    const int lane  = threadIdx.x & 63;
    const int wid   = threadIdx.x >> 6;             // K-split 0..3
    const int nch   = blockIdx.x;                   // 0..687
    const int nlo   = lane & 15;
    const int kq    = lane >> 4;                    // quad 0..3
    const int kbase = wid * KCHUNK + kq * 16;       // contiguous 16-float slice

    __shared__ float red[KSPLIT][TM][20];           // pad 20: 2-way max (free)
    __shared__ float bq[32];

    // quantized bias for this block's 32-wide MXFP block (cols nch*16..+15
    // are one aligned half of bias block nch>>1). Wave-0 lanes 0..31 only.
    if (threadIdx.x < 32) {
        float v = bias[(nch >> 1) * 32 + threadIdx.x];
        float am = fabsf(v);
        am = fmaxf(am, __shfl_xor(am, 1));
        am = fmaxf(am, __shfl_xor(am, 2));
        am = fmaxf(am, __shfl_xor(am, 4));
        am = fmaxf(am, __shfl_xor(am, 8));
        am = fmaxf(am, __shfl_xor(am, 16));
        float scale, inv;
        mx_block_scale(am, scale, inv);
        bq[threadIdx.x] = mx_qd(v, scale, inv);
    }

    const float*          wp = wgt  + (size_t)(nch * 16 + nlo) * DIN + kbase;
    const unsigned short* xp = x_dq + (size_t)nlo * DIN + kbase;

    f32x4 acc0 = {0.f,0.f,0.f,0.f};
    f32x4 acc1 = {0.f,0.f,0.f,0.f};
    f32x4 acc2 = {0.f,0.f,0.f,0.f};
    f32x4 acc3 = {0.f,0.f,0.f,0.f};

    // pipeline prologue: wa = W(macro k), wb = W(macro k+64) in flight,
    // scale for wa ready. Each macro tile = 16 contiguous floats per lane.
    float4 wa0 = *(const float4*)(wp);
    float4 wa1 = *(const float4*)(wp + 4);
    float4 wa2 = *(const float4*)(wp + 8);
    float4 wa3 = *(const float4*)(wp + 12);
    float4 wb0 = *(const float4*)(wp + 64);
    float4 wb1 = *(const float4*)(wp + 68);
    float4 wb2 = *(const float4*)(wp + 72);
    float4 wb3 = *(const float4*)(wp + 76);
    float am = blk_absmax16(wa0, wa1, wa2, wa3);
    am = fmaxf(am, __shfl_xor(am, 16));             // partner quad, same block
    float scale, inv;
    mx_block_scale(am, scale, inv);

    #pragma unroll 2
    for (int kk = 0; kk < KCHUNK; kk += 64) {
        // issue W(k+128); clamp keeps the last iterations in-bounds (dup load)
        const int kpre = (kk + 128 < KCHUNK) ? kk + 128 : KCHUNK - 64;
        float4 wc0 = *(const float4*)(wp + kpre);
        float4 wc1 = *(const float4*)(wp + kpre + 4);
        float4 wc2 = *(const float4*)(wp + kpre + 8);
        float4 wc3 = *(const float4*)(wp + kpre + 12);

        // A fragments (x_dq is 512 KB, L2-resident), natural k order:
        // frag0 = x[row][q*16 + 0..7], frag1 = x[row][q*16 + 8..15]
        bf16x8 a00 = *(const bf16x8*)(xp + kk);
        bf16x8 a01 = *(const bf16x8*)(xp + kk + 8);
        bf16x8 a10 = *(const bf16x8*)(xp + 16 * DIN + kk);
        bf16x8 a11 = *(const bf16x8*)(xp + 16 * DIN + kk + 8);
        bf16x8 a20 = *(const bf16x8*)(xp + 32 * DIN + kk);
        bf16x8 a21 = *(const bf16x8*)(xp + 32 * DIN + kk + 8);
        bf16x8 a30 = *(const bf16x8*)(xp + 48 * DIN + kk);
        bf16x8 a31 = *(const bf16x8*)(xp + 48 * DIN + kk + 8);

        // quantize current 16-elem slice with the pre-computed block scale
        bf16x8 bf0, bf1;
        bf0[0] = bf16_trunc(mx_qd(wa0.x, scale, inv));
        bf0[1] = bf16_trunc(mx_qd(wa0.y, scale, inv));
        bf0[2] = bf16_trunc(mx_qd(wa0.z, scale, inv));
        bf0[3] = bf16_trunc(mx_qd(wa0.w, scale, inv));
        bf0[4] = bf16_trunc(mx_qd(wa1.x, scale, inv));
        bf0[5] = bf16_trunc(mx_qd(wa1.y, scale, inv));
        bf0[6] = bf16_trunc(mx_qd(wa1.z, scale, inv));
        bf0[7] = bf16_trunc(mx_qd(wa1.w, scale, inv));
        bf1[0] = bf16_trunc(mx_qd(wa2.x, scale, inv));
        bf1[1] = bf16_trunc(mx_qd(wa2.y, scale, inv));
        bf1[2] = bf16_trunc(mx_qd(wa2.z, scale, inv));
        bf1[3] = bf16_trunc(mx_qd(wa2.w, scale, inv));
        bf1[4] = bf16_trunc(mx_qd(wa3.x, scale, inv));
        bf1[5] = bf16_trunc(mx_qd(wa3.y, scale, inv));
        bf1[6] = bf16_trunc(mx_qd(wa3.z, scale, inv));
        bf1[7] = bf16_trunc(mx_qd(wa3.w, scale, inv));

        acc0 = __builtin_amdgcn_mfma_f32_16x16x32_bf16(a00, bf0, acc0, 0, 0, 0);
        acc1 = __builtin_amdgcn_mfma_f32_16x16x32_bf16(a10, bf0, acc1, 0, 0, 0);
        acc2 = __builtin_amdgcn_mfma_f32_16x16x32_bf16(a20, bf0, acc2, 0, 0, 0);
        acc3 = __builtin_amdgcn_mfma_f32_16x16x32_bf16(a30, bf0, acc3, 0, 0, 0);
        acc0 = __builtin_amdgcn_mfma_f32_16x16x32_bf16(a01, bf1, acc0, 0, 0, 0);
        acc1 = __builtin_amdgcn_mfma_f32_16x16x32_bf16(a11, bf1, acc1, 0, 0, 0);
        acc2 = __builtin_amdgcn_mfma_f32_16x16x32_bf16(a21, bf1, acc2, 0, 0, 0);
        acc3 = __builtin_amdgcn_mfma_f32_16x16x32_bf16(a31, bf1, acc3, 0, 0, 0);

        // scale for the NEXT macro tile (wb arrived long ago); shfl latency
        // overlaps the MFMAs just issued
        float amn = blk_absmax16(wb0, wb1, wb2, wb3);
        amn = fmaxf(amn, __shfl_xor(amn, 16));
        mx_block_scale(amn, scale, inv);

        wa0 = wb0; wa1 = wb1; wa2 = wb2; wa3 = wb3;
        wb0 = wc0; wb1 = wc1; wb2 = wc2; wb3 = wc3;
    }

    // C/D map: col(n)=lane&15, row(m)=quad*4+reg (verified: absmax 0)
    const int mrow = kq * 4;
    #pragma unroll
    for (int r = 0; r < 4; ++r) {
        red[wid][mrow + r][nlo]      = acc0[r];
        red[wid][16 + mrow + r][nlo] = acc1[r];
        red[wid][32 + mrow + r][nlo] = acc2[r];
        red[wid][48 + mrow + r][nlo] = acc3[r];
    }
    __syncthreads();

    // 4 outputs per thread; strict left-to-right split sum
    const int col  = threadIdx.x & 15;
    const int row0 = threadIdx.x >> 4;              // 0..15
    const float b  = bq[((nch & 1) << 4) + col];
    float* op = out + (size_t)nch * 16 + col;
    #pragma unroll
    for (int t = 0; t < 4; ++t) {
        const int row = row0 + 16 * t;
        float s = ((red[0][row][col] + red[1][row][col]) + red[2][row][col]) + red[3][row][col];
        op[(size_t)row * DOUT] = s + b;
    }
}

extern "C" void kernel_launch(void* const* d_in, const int* in_sizes, int n_in,
                              void* d_out, int out_size, void* d_ws, size_t ws_size,
                              hipStream_t stream) {
    const float* x    = (const float*)d_in[0];   // [64, 4096]
    const float* wgt  = (const float*)d_in[1];   // [11008, 4096]
    const float* bias = (const float*)d_in[2];   // [11008]
    float* out = (float*)d_out;                  // [64, 11008]

    unsigned short* x_dq = (unsigned short*)d_ws;    // 512 KB (only ws use now)

    quant_x_kernel<<<256, 256, 0, stream>>>(x, x_dq);
    gemm_fused_kernel<<<NCHUNKS, 256, 0, stream>>>(x_dq, wgt, bias, out);
}